// Round 14
// baseline (438.999 us; speedup 1.0000x reference)
//
#include <hip/hip_runtime.h>

#define D_DIM 256
#define K_CODES 1024
#define T_DIM 4096
#define MTILE 128
#define NCHUNK 32
#define NCHUNKS 32
#define HCHUNK_BYTES 16384                  // 16 ks x 1024 B hi-fragments
#define W_GAP 0.0625f

// ws layout
#define IMG_OFF 4096
#define CNT_OFF (4096 + 512 * 1024)
#define WL_OFF  (CNT_OFF + 128)

typedef _Float16 f16x8 __attribute__((ext_vector_type(8)));
typedef float    f32x16 __attribute__((ext_vector_type(16)));

#define ZERO16 {0.f,0.f,0.f,0.f,0.f,0.f,0.f,0.f,0.f,0.f,0.f,0.f,0.f,0.f,0.f,0.f}

// --- prep 1: eN[k] = ||E[k]||^2 (fp64 accum) ---
__global__ __launch_bounds__(256) void vq_norm_kernel(const float* __restrict__ E,
                                                      float* __restrict__ eN) {
    __shared__ double wsum[4];
    const int k = blockIdx.x;
    const int tid = threadIdx.x;
    float v = E[(size_t)k * D_DIM + tid];
    double s = (double)v * (double)v;
    #pragma unroll
    for (int off = 32; off > 0; off >>= 1)
        s += __shfl_down(s, off);
    if ((tid & 63) == 0) wsum[tid >> 6] = s;
    __syncthreads();
    if (tid == 0) eN[k] = (float)((wsum[0] + wsum[1]) + (wsum[2] + wsum[3]));
}

// --- prep 2: E -> f16 HI-only 32x32x16 B-fragment image (512 KB) ---
__global__ __launch_bounds__(256) void vq_prep_e(const float* __restrict__ E,
                                                 char* __restrict__ img) {
    const int g    = blockIdx.x * 256 + threadIdx.x;   // 0..32767
    const int c    = g >> 10;          // chunk 0..31
    const int ks   = (g >> 6) & 15;    // k-step 0..15
    const int lane = g & 63;
    const int code = c * NCHUNK + (lane & 31);
    const int k0   = ks * 16 + (lane >> 5) * 8;
    const float* src = E + (size_t)code * D_DIM + k0;
    f16x8 hi;
    #pragma unroll
    for (int j = 0; j < 8; ++j) hi[j] = (_Float16)src[j];
    *(f16x8*)(img + (size_t)c * HCHUNK_BYTES + (size_t)ks * 1024 + lane * 16) = hi;
}

__global__ void vq_init(int* cnt) { if (threadIdx.x == 0) *cnt = 0; }

__device__ __forceinline__ void stage_chunk16(const char* gsrc, char* ldsdst, int tid) {
    const int lane = tid & 63;
    const int woff = (tid >> 6) << 10;   // wave*1024
    #pragma unroll
    for (int r = 0; r < 4; ++r) {
        __builtin_amdgcn_global_load_lds(
            (const __attribute__((address_space(1))) void*)(gsrc + r * 4096 + woff + (size_t)lane * 16),
            (__attribute__((address_space(3))) void*)(ldsdst + r * 4096 + woff),
            16, 0, 0);
    }
}

// Stage 1: hi*hi approx pass, min1/min2 tracking, gap-certified winner,
// flagged points appended to a global worklist for exact fix-up.
__global__ __launch_bounds__(256, 2) void vq_stage1(const float* __restrict__ z,
                                                    const float* __restrict__ E,
                                                    const float* __restrict__ eN_g,
                                                    const char* __restrict__ imgE,
                                                    int* __restrict__ cnt,
                                                    int* __restrict__ wl,
                                                    float* __restrict__ out) {
    __shared__ __align__(16) char lds_all[2 * HCHUNK_BYTES + 4096 + 512];
    char*  lds_e = lds_all;
    float* eN_s  = (float*)(lds_all + 2 * HCHUNK_BYTES);
    int*   idx_s = (int*)(lds_all + 2 * HCHUNK_BYTES + 4096);

    const int tid  = threadIdx.x;
    const int lane = tid & 63;
    const int w    = tid >> 6;        // wave 0..3
    const int l31  = lane & 31;
    const int khal = lane >> 5;
    const int bb   = blockIdx.y;
    const int t0b  = blockIdx.x * MTILE;

    // ---- A fragments: z_hi ONLY (64 regs). No lo pass in stage 1.
    const float* zb = z + (size_t)bb * D_DIM * T_DIM + t0b;
    const int tcol = w * 32 + l31;
    f16x8 a_hi[16];
    #pragma unroll
    for (int ks = 0; ks < 16; ++ks)
        #pragma unroll
        for (int j = 0; j < 8; ++j)
            a_hi[ks][j] = (_Float16)zb[(size_t)(ks * 16 + khal * 8 + j) * T_DIM + tcol];

    for (int i = tid; i < K_CODES; i += 256) eN_s[i] = eN_g[i];
    stage_chunk16(imgE, lds_e, tid);
    __syncthreads();

    float d1[16], d2[16];
    int   k1[16];
    #pragma unroll
    for (int r = 0; r < 16; ++r) {
        d1[r] = __builtin_huge_valf(); d2[r] = __builtin_huge_valf(); k1[r] = 0;
    }

    for (int c = 0; c < NCHUNKS; ++c) {
        const char* ebuf = lds_e + (c & 1) * HCHUNK_BYTES;
        if (c + 1 < NCHUNKS)
            stage_chunk16(imgE + (size_t)(c + 1) * HCHUNK_BYTES,
                          lds_e + ((c + 1) & 1) * HCHUNK_BYTES, tid);

        const int   n  = c * NCHUNK + l31;
        const float en = eN_s[n];

        f32x16 acc0 = ZERO16, acc1 = ZERO16;
        #pragma unroll
        for (int ks = 0; ks < 16; ks += 2) {
            f16x8 b0 = *(const f16x8*)(ebuf + (size_t)ks * 1024 + lane * 16);
            f16x8 b1 = *(const f16x8*)(ebuf + (size_t)(ks + 1) * 1024 + lane * 16);
            acc0 = __builtin_amdgcn_mfma_f32_32x32x16_f16(a_hi[ks],     b0, acc0, 0, 0, 0);
            acc1 = __builtin_amdgcn_mfma_f32_32x32x16_f16(a_hi[ks + 1], b1, acc1, 0, 0, 0);
        }

        #pragma unroll
        for (int r = 0; r < 16; ++r) {
            float dist = fmaf(-2.0f, acc0[r] + acc1[r], en);
            if (dist < d1[r]) { d2[r] = d1[r]; d1[r] = dist; k1[r] = n; }
            else if (dist < d2[r]) { d2[r] = dist; }
        }
        __syncthreads();
    }

    // ---- cross-lane (min1,min2) merge over the 32 code-columns
    #pragma unroll
    for (int off = 1; off < 32; off <<= 1) {
        #pragma unroll
        for (int r = 0; r < 16; ++r) {
            float od1 = __shfl_xor(d1[r], off, 64);
            int   ok1 = __shfl_xor(k1[r], off, 64);
            float od2 = __shfl_xor(d2[r], off, 64);
            bool take = (od1 < d1[r]) || (od1 == d1[r] && ok1 < k1[r]);
            float nd2 = take ? fminf(d1[r], od2) : fminf(d2[r], od1);
            d1[r] = take ? od1 : d1[r];
            k1[r] = take ? ok1 : k1[r];
            d2[r] = nd2;
        }
    }
    if (l31 == 0) {
        #pragma unroll
        for (int r = 0; r < 16; ++r) {
            const int row = (r & 3) + 8 * (r >> 2) + 4 * khal;   // verified C/D map
            idx_s[w * 32 + row] = k1[r];
            if (d2[r] - d1[r] <= W_GAP) {           // ambiguous: exact fix-up
                int pos = atomicAdd(cnt, 1);
                wl[pos] = (bb << 12) | (t0b + w * 32 + row);
            }
        }
    }
    __syncthreads();

    // ---- provisional gather (flagged rows rewritten by vq_fixup)
    const int p  = tid & 127;
    const int dh = tid >> 7;
    const int kk = idx_s[p];
    const float* er = E + (size_t)kk * D_DIM + dh * 128;
    float* ob = out + (size_t)bb * D_DIM * T_DIM + t0b + p;
    #pragma unroll 8
    for (int i = 0; i < 128; ++i)
        ob[(size_t)(dh * 128 + i) * T_DIM] = er[i];
}

// Stage 2: exact f64 full rescan for flagged points (one wave per point).
__global__ __launch_bounds__(256) void vq_fixup(const float* __restrict__ z,
                                                const float* __restrict__ E,
                                                const int* __restrict__ cnt,
                                                const int* __restrict__ wl,
                                                float* __restrict__ out) {
    __shared__ float zcol[4][D_DIM];
    const int w = threadIdx.x >> 6, lane = threadIdx.x & 63;
    const int gw = blockIdx.x * 4 + w;
    const int count = cnt[0];
    for (int it = gw; it < count; it += 1024) {
        const int P = wl[it];
        const int b = P >> 12, t = P & 4095;
        const float* zb = z + (size_t)b * D_DIM * T_DIM + t;
        #pragma unroll
        for (int i = 0; i < 4; ++i)
            zcol[w][lane * 4 + i] = zb[(size_t)(lane * 4 + i) * T_DIM];
        asm volatile("s_waitcnt vmcnt(0) lgkmcnt(0)" ::: "memory");  // wave-local publish

        double bd = 1e300; int bk = 0;
        for (int i = 0; i < 16; ++i) {
            const int k = lane * 16 + i;                // ascending k per lane
            const float* er = E + (size_t)k * D_DIM;
            double s = 0.0;
            #pragma unroll 4
            for (int d = 0; d < D_DIM; ++d) {
                double diff = (double)zcol[w][d] - (double)er[d];
                s = fma(diff, diff, s);
            }
            if (s < bd) { bd = s; bk = k; }             // strict <: first-min
        }
        #pragma unroll
        for (int off = 1; off < 64; off <<= 1) {
            double od = __shfl_xor(bd, off, 64);
            int    ok = __shfl_xor(bk, off, 64);
            if (od < bd || (od == bd && ok < bk)) { bd = od; bk = ok; }
        }
        const float* er = E + (size_t)bk * D_DIM;
        float* ob = out + (size_t)b * D_DIM * T_DIM + t;
        #pragma unroll
        for (int i = 0; i < 4; ++i)
            ob[(size_t)(lane * 4 + i) * T_DIM] = er[lane * 4 + i];
    }
}

extern "C" void kernel_launch(void* const* d_in, const int* in_sizes, int n_in,
                              void* d_out, int out_size, void* d_ws, size_t ws_size,
                              hipStream_t stream) {
    const float* z = (const float*)d_in[0];
    const float* E = (const float*)d_in[1];
    float* out = (float*)d_out;
    float* eN  = (float*)d_ws;
    char*  img = (char*)d_ws + IMG_OFF;
    int*   cnt = (int*)((char*)d_ws + CNT_OFF);
    int*   wl  = (int*)((char*)d_ws + WL_OFF);

    const int B = in_sizes[0] / (D_DIM * T_DIM);   // 32

    vq_norm_kernel<<<dim3(K_CODES), dim3(256), 0, stream>>>(E, eN);
    vq_prep_e<<<dim3(128), dim3(256), 0, stream>>>(E, img);
    vq_init<<<dim3(1), dim3(64), 0, stream>>>(cnt);

    dim3 grid(T_DIM / MTILE, B);
    vq_stage1<<<grid, dim3(256), 0, stream>>>(z, E, eN, img, cnt, wl, out);
    vq_fixup<<<dim3(256), dim3(256), 0, stream>>>(z, E, cnt, wl, out);
}

// Round 15
// 208.176 us; speedup vs baseline: 2.1088x; 2.1088x over previous
//
#include <hip/hip_runtime.h>

#define D_DIM 256
#define K_CODES 1024
#define T_DIM 4096
#define MTILE 128
#define NCHUNK 32
#define NCHUNKS (K_CODES / NCHUNK)          // 32
#define PART_BYTES (NCHUNK * D_DIM * 2)     // 16384 (one f16 part of a chunk)
#define CHUNK_BYTES (2 * PART_BYTES)        // 32768 (hi+lo)

typedef _Float16 f16x8 __attribute__((ext_vector_type(8)));
typedef float    f32x4 __attribute__((ext_vector_type(4)));

// ws layout: [0,4096): eN f32[1024]; [4096, 4096+1 MiB): swizzled E image (f16 hi/lo)

// --- prep 1: eN[k] = ||E[k]||^2 (fp64 accum) ---
__global__ __launch_bounds__(256) void vq_norm_kernel(const float* __restrict__ E,
                                                      float* __restrict__ eN) {
    __shared__ double wsum[4];
    const int k = blockIdx.x;
    const int tid = threadIdx.x;
    float v = E[(size_t)k * D_DIM + tid];
    double s = (double)v * (double)v;
    #pragma unroll
    for (int off = 32; off > 0; off >>= 1)
        s += __shfl_down(s, off);
    if ((tid & 63) == 0) wsum[tid >> 6] = s;
    __syncthreads();
    if (tid == 0) eN[k] = (float)((wsum[0] + wsum[1]) + (wsum[2] + wsum[3]));
}

// --- prep 2: E -> f16 hi/lo, stored as the pre-swizzled LDS chunk image ---
__global__ __launch_bounds__(256) void vq_prep_e(const float* __restrict__ E,
                                                 char* __restrict__ img) {
    const int g  = blockIdx.x * 256 + threadIdx.x;   // 0..32767
    const int k  = g >> 5;                           // code 0..1023
    const int dg = g & 31;                           // d-group of 8
    const float* src = E + (size_t)k * D_DIM + dg * 8;
    f16x8 hi, lo;
    #pragma unroll
    for (int j = 0; j < 8; ++j) {
        float v = src[j];
        _Float16 h = (_Float16)v;
        hi[j] = h;
        lo[j] = (_Float16)(v - (float)h);
    }
    const int chunk = k >> 5, code = k & 31;
    size_t off = (size_t)chunk * CHUNK_BYTES + code * 512 + ((dg * 16) ^ ((code & 7) << 4));
    *(f16x8*)(img + off) = hi;
    *(f16x8*)(img + off + PART_BYTES) = lo;
}

__device__ __forceinline__ void stage_chunk(const char* gsrc, char* ldsdst, int tid) {
    const int lane = tid & 63;
    const int woff = (tid >> 6) << 10;   // wave*1024
    #pragma unroll
    for (int r = 0; r < 8; ++r) {
        __builtin_amdgcn_global_load_lds(
            (const __attribute__((address_space(1))) void*)(gsrc + r * 4096 + woff + (size_t)lane * 16),
            (__attribute__((address_space(3))) void*)(ldsdst + r * 4096 + woff),
            16, 0, 0);
    }
}

__global__ __launch_bounds__(256, 2) void vq_mfma_kernel(const float* __restrict__ z,
                                                         const float* __restrict__ E,
                                                         const float* __restrict__ eN_g,
                                                         const char* __restrict__ imgE,
                                                         float* __restrict__ out) {
    __shared__ __align__(16) char lds_all[2 * CHUNK_BYTES + 4096 + 512];
    char*  lds_e = lds_all;
    float* eN_s  = (float*)(lds_all + 2 * CHUNK_BYTES);
    int*   idx_s = (int*)(lds_all + 2 * CHUNK_BYTES + 4096);

    const int tid  = threadIdx.x;
    const int lane = tid & 63;
    const int w    = tid >> 6;        // wave 0..3
    const int l15  = lane & 15;
    const int kg   = lane >> 4;       // 0..3
    const int bb   = blockIdx.y;
    const int t0   = blockIdx.x * MTILE;

    // ---- A fragments: z loaded straight from global (coalesced), f16 hi/lo split.
    // ~128 regs on the AGPR side of the unified file -> occupancy is reg-capped
    // at 2 waves/SIMD; launch_bounds min-waves stays 2 (round-6 spill proof).
    const float* zb = z + (size_t)bb * D_DIM * T_DIM + t0;
    f16x8 a_hi[2][8], a_lo[2][8];
    #pragma unroll
    for (int s = 0; s < 2; ++s) {
        const int tcol = w * 32 + s * 16 + l15;
        #pragma unroll
        for (int ks = 0; ks < 8; ++ks) {
            #pragma unroll
            for (int j = 0; j < 8; ++j) {
                float v = zb[(size_t)(ks * 32 + kg * 8 + j) * T_DIM + tcol];
                _Float16 h = (_Float16)v;
                a_hi[s][ks][j] = h;
                a_lo[s][ks][j] = (_Float16)(v - (float)h);
            }
        }
    }

    // ---- stage eN + first E chunk, then one full-drain barrier (prologue only)
    for (int i = tid; i < K_CODES; i += 256) eN_s[i] = eN_g[i];
    stage_chunk(imgE, lds_e, tid);
    __syncthreads();   // drains vmcnt(0): chunk 0 staged, eN_s visible

    float best[2][4];
    int   bestk[2][4];
    #pragma unroll
    for (int s = 0; s < 2; ++s)
        #pragma unroll
        for (int r = 0; r < 4; ++r) { best[s][r] = __builtin_huge_valf(); bestk[s][r] = 0; }

    for (int c = 0; c < NCHUNKS; ++c) {
        const char* ebuf = lds_e + (c & 1) * CHUNK_BYTES;

        // T4 counted-vmcnt pipeline: issue next-chunk stage, wait ONLY for the
        // current chunk's loads (8 newest may stay in flight across the barrier).
        if (c + 1 < NCHUNKS) {
            stage_chunk(imgE + (size_t)(c + 1) * CHUNK_BYTES,
                        lds_e + ((c + 1) & 1) * CHUNK_BYTES, tid);
            asm volatile("s_waitcnt vmcnt(8)" ::: "memory");
        } else {
            asm volatile("s_waitcnt vmcnt(0)" ::: "memory");
        }
        __builtin_amdgcn_s_barrier();          // publish all waves' staged slices
        __builtin_amdgcn_sched_barrier(0);     // rule #18: no hoisting past the wait

        #pragma unroll
        for (int nt = 0; nt < 2; ++nt) {
            const int  cl    = nt * 16 + l15;
            const int  swz   = (cl & 7) << 4;
            const char* bbase = ebuf + cl * 512;

            // per-lane code norm, loaded BEFORE the MFMA cluster (latency hidden)
            const float en = eN_s[c * NCHUNK + cl];

            // 6 independent accumulator chains: [strip][pass]
            f32x4 aH[2], aM[2], aL[2];
            #pragma unroll
            for (int s = 0; s < 2; ++s) {
                aH[s] = (f32x4){0.f, 0.f, 0.f, 0.f};
                aM[s] = (f32x4){0.f, 0.f, 0.f, 0.f};
                aL[s] = (f32x4){0.f, 0.f, 0.f, 0.f};
            }

            // NO setprio: barrier-lockstep 2-wave blocks have no role diversity;
            // m190 measured setprio as negative on exactly this structure, and
            // our best MfmaUtil (46%, round 2) was the no-setprio variant.
            #pragma unroll
            for (int ks = 0; ks < 8; ++ks) {
                const int ko = (ks * 64 + kg * 16) ^ swz;
                f16x8 bh = *(const f16x8*)(bbase + ko);
                f16x8 bl = *(const f16x8*)(bbase + ko + PART_BYTES);
                #pragma unroll
                for (int s = 0; s < 2; ++s)
                    aH[s] = __builtin_amdgcn_mfma_f32_16x16x32_f16(a_hi[s][ks], bh, aH[s], 0, 0, 0);
                #pragma unroll
                for (int s = 0; s < 2; ++s)
                    aM[s] = __builtin_amdgcn_mfma_f32_16x16x32_f16(a_hi[s][ks], bl, aM[s], 0, 0, 0);
                #pragma unroll
                for (int s = 0; s < 2; ++s)
                    aL[s] = __builtin_amdgcn_mfma_f32_16x16x32_f16(a_lo[s][ks], bh, aL[s], 0, 0, 0);
            }

            const int n = c * NCHUNK + cl;
            #pragma unroll
            for (int s = 0; s < 2; ++s) {
                f32x4 dsum = (aH[s] + aM[s]) + aL[s];
                #pragma unroll
                for (int r = 0; r < 4; ++r) {
                    float dist = fmaf(-2.0f, dsum[r], en);
                    // strict < with ascending n == first-min tie-break (matches jnp.argmin)
                    if (dist < best[s][r]) { best[s][r] = dist; bestk[s][r] = n; }
                }
            }
        }

        // my ds_reads of ebuf were consumed by MFMAs (lgkmcnt ordered) — safe
        // for other waves to overwrite ebuf after this barrier. vmcnt NOT drained.
        __builtin_amdgcn_sched_barrier(0);
        __builtin_amdgcn_s_barrier();
    }

    // ---- cross-lane argmin reduce over the 16 columns (bits 0-3 of lane)
    #pragma unroll
    for (int off = 1; off < 16; off <<= 1) {
        #pragma unroll
        for (int s = 0; s < 2; ++s) {
            #pragma unroll
            for (int r = 0; r < 4; ++r) {
                float od = __shfl_xor(best[s][r], off, 64);
                int   ok = __shfl_xor(bestk[s][r], off, 64);
                if (od < best[s][r] || (od == best[s][r] && ok < bestk[s][r])) {
                    best[s][r] = od; bestk[s][r] = ok;
                }
            }
        }
    }
    if (l15 == 0) {
        #pragma unroll
        for (int s = 0; s < 2; ++s)
            #pragma unroll
            for (int r = 0; r < 4; ++r)
                idx_s[w * 32 + s * 16 + kg * 4 + r] = bestk[s][r];
    }
    __syncthreads();

    // ---- fused gather: out[b][d][t0+p] = E[idx[p]][d]
    const int p  = tid & 127;
    const int dh = tid >> 7;
    const int kk = idx_s[p];
    const float* er = E + (size_t)kk * D_DIM + dh * 128;
    float* ob = out + (size_t)bb * D_DIM * T_DIM + t0 + p;
    #pragma unroll 8
    for (int i = 0; i < 128; ++i)
        ob[(size_t)(dh * 128 + i) * T_DIM] = er[i];
}

extern "C" void kernel_launch(void* const* d_in, const int* in_sizes, int n_in,
                              void* d_out, int out_size, void* d_ws, size_t ws_size,
                              hipStream_t stream) {
    const float* z = (const float*)d_in[0];
    const float* E = (const float*)d_in[1];
    float* out = (float*)d_out;
    float* eN  = (float*)d_ws;
    char*  img = (char*)d_ws + 4096;

    const int B = in_sizes[0] / (D_DIM * T_DIM);   // 32

    vq_norm_kernel<<<dim3(K_CODES), dim3(256), 0, stream>>>(E, eN);
    vq_prep_e<<<dim3((K_CODES * NCHUNK) / 256), dim3(256), 0, stream>>>(E, img);

    dim3 grid(T_DIM / MTILE, B);
    vq_mfma_kernel<<<grid, dim3(256), 0, stream>>>(z, E, eN, img, out);
}